// Round 5
// baseline (155.195 us; speedup 1.0000x reference)
//
#include <hip/hip_runtime.h>
#include <stdint.h>

#define B_    16
#define CIN_  128
#define COUT_ 128
#define H_    64
#define W_    64
#define L_    4096
#define KK_   1152
#define PW_   66                 // padded image dim (halo 1 each side)

typedef unsigned short u16;
typedef __bf16 bf16x8 __attribute__((ext_vector_type(8)));
typedef float  floatx4 __attribute__((ext_vector_type(4)));
typedef uint32_t u32x4 __attribute__((ext_vector_type(4)));

typedef const __attribute__((address_space(1))) uint32_t* gptr_t;
typedef __attribute__((address_space(3))) uint32_t*       lptr_t;

__device__ __forceinline__ void async_copy16(const void* g, void* l) {
    // 64 lanes x 16 B = 1 KB; LDS dest = wave-uniform base + lane*16
    __builtin_amdgcn_global_load_lds((gptr_t)g, (lptr_t)l, 16, 0, 0);
}

__device__ __forceinline__ u16 f2bf(float f) {
    uint32_t u = __builtin_bit_cast(uint32_t, f);
    uint32_t r = u + 0x7FFFu + ((u >> 16) & 1u);   // round-to-nearest-even
    return (u16)(r >> 16);
}

// ---------------------------------------------------------------------------
// P1 fused: blockIdx.y < 16 : x [B][CIN][64][64] f32 -> xTp [B][66][66][CIN] bf16
//           blockIdx.y ==16 : mb[o][l] precompute + weight reorder wb2[k][o][c]
// ---------------------------------------------------------------------------
__global__ void lmc_pre_kernel(const float* __restrict__ x, u16* __restrict__ xTp,
                               const float* __restrict__ mask, const float* __restrict__ mw,
                               const float* __restrict__ bias, const float* __restrict__ w,
                               float* __restrict__ mb, u16* __restrict__ wb2) {
    __shared__ u16 tile[64][CIN_ + 8];
    const int tid = threadIdx.x;

    if (blockIdx.y == 16) {
        const int bid = blockIdx.x;
        const int base = bid * 2304;
        #pragma unroll
        for (int i = 0; i < 9; ++i) {
            const int e = base + i * 256 + tid;
            const int k = e >> 14;
            const int rem = e & 16383;
            const int o = rem >> 7, c = rem & 127;
            wb2[e] = f2bf(w[(size_t)o * KK_ + c * 9 + k]);
        }
        #pragma unroll
        for (int oo = 0; oo < 2; ++oo) {
            const int o = bid * 2 + oo;
            float m[9];
            #pragma unroll
            for (int k = 0; k < 9; ++k) m[k] = mw[o * 9 + k];
            const float bs = bias[o];
            for (int l = tid; l < L_; l += 256) {
                float s = bs;
                #pragma unroll
                for (int k = 0; k < 9; ++k) s += m[k] * mask[k * L_ + l];
                mb[o * L_ + l] = s;
            }
        }
        return;
    }

    const int b = blockIdx.y;
    const int y = blockIdx.x;        // 0..63
    {
        const int c  = tid >> 1;
        const int x0 = (tid & 1) * 32;
        const float* src = x + ((size_t)b * CIN_ + c) * L_ + y * 64 + x0;
        #pragma unroll
        for (int j = 0; j < 32; j += 4) {
            float4 v = *reinterpret_cast<const float4*>(src + j);
            tile[x0 + j + 0][c] = f2bf(v.x);
            tile[x0 + j + 1][c] = f2bf(v.y);
            tile[x0 + j + 2][c] = f2bf(v.z);
            tile[x0 + j + 3][c] = f2bf(v.w);
        }
    }
    __syncthreads();

    u16* dstrow = xTp + ((size_t)(b * PW_ + (y + 1)) * PW_) * CIN_;  // pixel (y+1, 0)
    {
        const int xx   = tid >> 2;
        const int cseg = (tid & 3) * 32;
        u16* dst = dstrow + (size_t)(xx + 1) * CIN_ + cseg;
        #pragma unroll
        for (int i = 0; i < 32; i += 8) {
            *reinterpret_cast<uint4*>(dst + i) =
                *reinterpret_cast<const uint4*>(&tile[xx][cseg + i]);
        }
    }
    const uint4 z = {0u, 0u, 0u, 0u};
    if (tid < 32) {   // x-halo pixels (y+1, 0) and (y+1, 65)
        const int pix = (tid >> 4) ? 65 : 0;
        *reinterpret_cast<uint4*>(dstrow + (size_t)pix * CIN_ + (tid & 15) * 8) = z;
    }
    if (y == 0 || y == 63) {   // y-halo rows 0 / 65
        u16* brow = xTp + ((size_t)(b * PW_ + (y == 0 ? 0 : 65)) * PW_) * CIN_;
        for (int i = tid; i < (PW_ * CIN_) / 8; i += 256)
            reinterpret_cast<uint4*>(brow)[i] = z;
    }
}

// ---------------------------------------------------------------------------
// Main GEMM, barrier-free K-loop + register-pipelined A:
//   - Bwin: 4 padded rows x 64 cols x 128 ch = 64 KB LDS, staged ONCE (XOR-8).
//   - A (weights): double-buffered in VGPRs; tap k+1's 16 b128 loads issue
//     before tap k's 64 MFMAs -> vmcnt(16)-style overlap, never a full drain.
//   - One __syncthreads total.
// ---------------------------------------------------------------------------
__global__ __launch_bounds__(256, 2)
void lmc_gemm_kernel(const u16* __restrict__ xTp, const u16* __restrict__ wb2,
                     const float* __restrict__ mask, const float* __restrict__ mb,
                     float* __restrict__ out) {
    __shared__ u16 Bwin[4 * 64 * 128];     // 64 KB: [row][col][chunk swizzled]

    const int b    = blockIdx.y;
    const int tile = blockIdx.x;           // 0..31, image rows {2t, 2t+1}
    const int l0   = tile * 128;
    const int tid  = threadIdx.x;
    const int lane = tid & 63;
    const int wv   = tid >> 6;
    const int wm   = (wv >> 1) * 64;
    const int wn   = (wv & 1) * 64;
    const int lrow = lane & 15;
    const int quad = lane >> 4;

    // ---- stage Bwin once: padded rows 2*tile .. 2*tile+3, interior cols 1..64
    {
        const char* srcrow = (const char*)xTp
            + ((size_t)((b * PW_) + tile * 2 + wv) * PW_ + 1) * 256;
        char* dst = (char*)Bwin + wv * 16384;   // wave wv stages row wv
        const int cl = lane >> 4;               // 0..3
        #pragma unroll
        for (int seg = 0; seg < 16; ++seg) {
            const int col = seg * 4 + cl;
            const int ch  = (lane & 15) ^ (col & 7);
            async_copy16(srcrow + col * 256 + ch * 16, dst + seg * 1024);
        }
    }

    // ---- pack 36 bits: bit(k,j) = mask[k][l] != 0  AND  x+dx in [0,64)
    uint64_t bits = 0;
    #pragma unroll
    for (int j = 0; j < 4; ++j) {
        const int xl  = j * 16 + lrow;           // 0..63
        const int l_g = l0 + wn + xl;
        #pragma unroll
        for (int k = 0; k < 9; ++k) {
            const int dx = k - (k / 3) * 3 - 1;
            const bool xok = (unsigned)(xl + dx) < 64u;
            if (xok && mask[k * L_ + l_g] != 0.0f) bits |= (1ull << (k * 4 + j));
        }
    }

    floatx4 acc[4][4];
    #pragma unroll
    for (int i = 0; i < 4; ++i)
        #pragma unroll
        for (int j = 0; j < 4; ++j)
            acc[i][j] = (floatx4){0.f, 0.f, 0.f, 0.f};

    int rowA[4];
    #pragma unroll
    for (int i = 0; i < 4; ++i) rowA[i] = (wm + i * 16 + lrow) * 256 + quad * 16;
    const int ywave = wn >> 6;                 // 0 or 1: wave's image row in tile
    const char* wb2_c = (const char*)wb2;
    const char* Bw = (const char*)Bwin;

    // ---- A register pipeline: preload tap 0 (16 x b128), q = ks*4 + i
    bf16x8 afb[2][16];
    #pragma unroll
    for (int q = 0; q < 16; ++q)
        afb[0][q] = *reinterpret_cast<const bf16x8*>(wb2_c + rowA[q & 3] + (q >> 2) * 64);

    __syncthreads();   // Bwin ready; no more barriers

    #pragma unroll
    for (int k = 0; k < 9; ++k) {
        const int cur = k & 1, nxt = cur ^ 1;
        // prefetch next tap's A before this tap's MFMAs (stays in flight)
        if (k < 8) {
            const char* An = wb2_c + (k + 1) * 32768;
            #pragma unroll
            for (int q = 0; q < 16; ++q)
                afb[nxt][q] = *reinterpret_cast<const bf16x8*>(An + rowA[q & 3] + (q >> 2) * 64);
        }

        const int dy = k / 3 - 1;              // constant-folded (loop unrolled)
        const int dx = k - (k / 3) * 3 - 1;
        const int rowbase = (ywave + 1 + dy) * 16384;   // Bwin row byte offset

        int baddr[4], c7[4];
        #pragma unroll
        for (int j = 0; j < 4; ++j) {
            int col = j * 16 + lrow + dx;
            col = min(max(col, 0), 63);        // clamp; OOB lanes masked by bits
            baddr[j] = rowbase + col * 256;
            c7[j] = col & 7;
        }
        uint32_t kp[4];
        #pragma unroll
        for (int j = 0; j < 4; ++j)
            kp[j] = 0u - (uint32_t)((bits >> (k * 4 + j)) & 1ull);

        #pragma unroll
        for (int ks = 0; ks < 4; ++ks) {
            bf16x8 bfr[4];
            #pragma unroll
            for (int j = 0; j < 4; ++j) {
                const int slot = ((ks * 4 + quad) ^ c7[j]) * 16;
                bf16x8 v = *reinterpret_cast<const bf16x8*>(Bw + baddr[j] + slot);
                u32x4 t = __builtin_bit_cast(u32x4, v);
                t &= kp[j];
                bfr[j] = __builtin_bit_cast(bf16x8, t);
            }
            #pragma unroll
            for (int i = 0; i < 4; ++i)
                #pragma unroll
                for (int j = 0; j < 4; ++j)
                    acc[i][j] = __builtin_amdgcn_mfma_f32_16x16x32_bf16(
                        afb[cur][ks * 4 + i], bfr[j], acc[i][j], 0, 0, 0);
        }
    }

    // ---- epilogue: C/D layout col = lane&15 (l), row = quad*4 + r (o)
    #pragma unroll
    for (int i = 0; i < 4; ++i) {
        #pragma unroll
        for (int j = 0; j < 4; ++j) {
            const int l = l0 + wn + j * 16 + lrow;
            #pragma unroll
            for (int r = 0; r < 4; ++r) {
                const int o = wm + i * 16 + quad * 4 + r;
                out[((size_t)b * COUT_ + o) * L_ + l] = acc[i][j][r] + mb[o * L_ + l];
            }
        }
    }
}

// ---------------------------------------------------------------------------
extern "C" void kernel_launch(void* const* d_in, const int* in_sizes, int n_in,
                              void* d_out, int out_size, void* d_ws, size_t ws_size,
                              hipStream_t stream) {
    const float* x      = (const float*)d_in[0];
    const float* mask   = (const float*)d_in[1];
    const float* weight = (const float*)d_in[2];
    const float* mw     = (const float*)d_in[3];
    const float* bias   = (const float*)d_in[4];
    float* out = (float*)d_out;

    char* ws = (char*)d_ws;
    u16*   xTp = (u16*)ws;                                  // 16*4356*128*2 = 17,842,176 B
    u16*   wb2 = (u16*)(ws + 17842176);                     // 294,912 B  [9][128][128] bf16
    float* mb  = (float*)(ws + 17842176 + 294912);          // 2,097,152 B [128][4096] f32

    lmc_pre_kernel<<<dim3(64, 17), 256, 0, stream>>>(x, xTp, mask, mw, bias, weight, mb, wb2);
    lmc_gemm_kernel<<<dim3(32, 16), 256, 0, stream>>>(xTp, wb2, mask, mb, out);
}

// Round 6
// 151.724 us; speedup vs baseline: 1.0229x; 1.0229x over previous
//
#include <hip/hip_runtime.h>
#include <stdint.h>

#define B_    16
#define CIN_  128
#define COUT_ 128
#define H_    64
#define W_    64
#define L_    4096
#define KK_   1152
#define PW_   66                 // padded image dim (halo 1 each side)

typedef unsigned short u16;
typedef __bf16 bf16x8 __attribute__((ext_vector_type(8)));
typedef float  floatx4 __attribute__((ext_vector_type(4)));
typedef uint32_t u32x4 __attribute__((ext_vector_type(4)));

typedef const __attribute__((address_space(1))) uint32_t* gptr_t;
typedef __attribute__((address_space(3))) uint32_t*       lptr_t;

__device__ __forceinline__ void async_copy16(const void* g, void* l) {
    // 64 lanes x 16 B = 1 KB; LDS dest = wave-uniform base + lane*16
    __builtin_amdgcn_global_load_lds((gptr_t)g, (lptr_t)l, 16, 0, 0);
}

__device__ __forceinline__ u16 f2bf(float f) {
    uint32_t u = __builtin_bit_cast(uint32_t, f);
    uint32_t r = u + 0x7FFFu + ((u >> 16) & 1u);   // round-to-nearest-even
    return (u16)(r >> 16);
}

// ---------------------------------------------------------------------------
// P1 fused: blockIdx.y < 16 : x [B][CIN][64][64] f32 -> xTp [B][66][66][CIN] bf16
//           blockIdx.y ==16 : mb[o][l] precompute + weight reorder wb2[k][o][c]
// ---------------------------------------------------------------------------
__global__ void lmc_pre_kernel(const float* __restrict__ x, u16* __restrict__ xTp,
                               const float* __restrict__ mask, const float* __restrict__ mw,
                               const float* __restrict__ bias, const float* __restrict__ w,
                               float* __restrict__ mb, u16* __restrict__ wb2) {
    __shared__ u16 tile[64][CIN_ + 8];
    const int tid = threadIdx.x;

    if (blockIdx.y == 16) {
        const int bid = blockIdx.x;
        const int base = bid * 2304;
        #pragma unroll
        for (int i = 0; i < 9; ++i) {
            const int e = base + i * 256 + tid;
            const int k = e >> 14;
            const int rem = e & 16383;
            const int o = rem >> 7, c = rem & 127;
            wb2[e] = f2bf(w[(size_t)o * KK_ + c * 9 + k]);
        }
        #pragma unroll
        for (int oo = 0; oo < 2; ++oo) {
            const int o = bid * 2 + oo;
            float m[9];
            #pragma unroll
            for (int k = 0; k < 9; ++k) m[k] = mw[o * 9 + k];
            const float bs = bias[o];
            for (int l = tid; l < L_; l += 256) {
                float s = bs;
                #pragma unroll
                for (int k = 0; k < 9; ++k) s += m[k] * mask[k * L_ + l];
                mb[o * L_ + l] = s;
            }
        }
        return;
    }

    const int b = blockIdx.y;
    const int y = blockIdx.x;        // 0..63
    {
        const int c  = tid >> 1;
        const int x0 = (tid & 1) * 32;
        const float* src = x + ((size_t)b * CIN_ + c) * L_ + y * 64 + x0;
        #pragma unroll
        for (int j = 0; j < 32; j += 4) {
            float4 v = *reinterpret_cast<const float4*>(src + j);
            tile[x0 + j + 0][c] = f2bf(v.x);
            tile[x0 + j + 1][c] = f2bf(v.y);
            tile[x0 + j + 2][c] = f2bf(v.z);
            tile[x0 + j + 3][c] = f2bf(v.w);
        }
    }
    __syncthreads();

    u16* dstrow = xTp + ((size_t)(b * PW_ + (y + 1)) * PW_) * CIN_;  // pixel (y+1, 0)
    {
        const int xx   = tid >> 2;
        const int cseg = (tid & 3) * 32;
        u16* dst = dstrow + (size_t)(xx + 1) * CIN_ + cseg;
        #pragma unroll
        for (int i = 0; i < 32; i += 8) {
            *reinterpret_cast<uint4*>(dst + i) =
                *reinterpret_cast<const uint4*>(&tile[xx][cseg + i]);
        }
    }
    const uint4 z = {0u, 0u, 0u, 0u};
    if (tid < 32) {   // x-halo pixels (y+1, 0) and (y+1, 65)
        const int pix = (tid >> 4) ? 65 : 0;
        *reinterpret_cast<uint4*>(dstrow + (size_t)pix * CIN_ + (tid & 15) * 8) = z;
    }
    if (y == 0 || y == 63) {   // y-halo rows 0 / 65
        u16* brow = xTp + ((size_t)(b * PW_ + (y == 0 ? 0 : 65)) * PW_) * CIN_;
        for (int i = tid; i < (PW_ * CIN_) / 8; i += 256)
            reinterpret_cast<uint4*>(brow)[i] = z;
    }
}

// ---------------------------------------------------------------------------
// Main GEMM, barrier-free K-loop + depth-2 A-ring prefetch:
//   - Bwin: 4 padded rows x 64 cols x 128 ch = 64 KB LDS, staged ONCE (XOR-8).
//   - A (weights): ring afr[2][4] (32 VGPR). Step s consumes frags loaded at
//     step s-2 (~250 cyc in flight, covers L2 latency); slot re-issued for
//     s+2 right after the MFMAs -> steady vmcnt(4), never a JIT stall.
//   - One __syncthreads total.
// ---------------------------------------------------------------------------
__global__ __launch_bounds__(256, 2)
void lmc_gemm_kernel(const u16* __restrict__ xTp, const u16* __restrict__ wb2,
                     const float* __restrict__ mask, const float* __restrict__ mb,
                     float* __restrict__ out) {
    __shared__ u16 Bwin[4 * 64 * 128];     // 64 KB: [row][col][chunk swizzled]

    const int b    = blockIdx.y;
    const int tile = blockIdx.x;           // 0..31, image rows {2t, 2t+1}
    const int l0   = tile * 128;
    const int tid  = threadIdx.x;
    const int lane = tid & 63;
    const int wv   = tid >> 6;
    const int wm   = (wv >> 1) * 64;
    const int wn   = (wv & 1) * 64;
    const int lrow = lane & 15;
    const int quad = lane >> 4;

    // ---- stage Bwin once: padded rows 2*tile .. 2*tile+3, interior cols 1..64
    {
        const char* srcrow = (const char*)xTp
            + ((size_t)((b * PW_) + tile * 2 + wv) * PW_ + 1) * 256;
        char* dst = (char*)Bwin + wv * 16384;   // wave wv stages row wv
        const int cl = lane >> 4;               // 0..3
        #pragma unroll
        for (int seg = 0; seg < 16; ++seg) {
            const int col = seg * 4 + cl;
            const int ch  = (lane & 15) ^ (col & 7);
            async_copy16(srcrow + col * 256 + ch * 16, dst + seg * 1024);
        }
    }

    // ---- pack 36 bits: bit(k,j) = mask[k][l] != 0  AND  x+dx in [0,64)
    uint64_t bits = 0;
    #pragma unroll
    for (int j = 0; j < 4; ++j) {
        const int xl  = j * 16 + lrow;           // 0..63
        const int l_g = l0 + wn + xl;
        #pragma unroll
        for (int k = 0; k < 9; ++k) {
            const int dx = k - (k / 3) * 3 - 1;
            const bool xok = (unsigned)(xl + dx) < 64u;
            if (xok && mask[k * L_ + l_g] != 0.0f) bits |= (1ull << (k * 4 + j));
        }
    }

    floatx4 acc[4][4];
    #pragma unroll
    for (int i = 0; i < 4; ++i)
        #pragma unroll
        for (int j = 0; j < 4; ++j)
            acc[i][j] = (floatx4){0.f, 0.f, 0.f, 0.f};

    int rowA[4];
    #pragma unroll
    for (int i = 0; i < 4; ++i) rowA[i] = (wm + i * 16 + lrow) * 256 + quad * 16;
    const int ywave = wn >> 6;                 // 0 or 1: wave's image row in tile
    const char* wb2_c = (const char*)wb2;
    const char* Bw = (const char*)Bwin;

    // ---- A ring prefetch: preload steps 0 and 1 (tap 0, ks 0/1)
    bf16x8 afr[2][4];
    #pragma unroll
    for (int i = 0; i < 4; ++i)
        afr[0][i] = *reinterpret_cast<const bf16x8*>(wb2_c + rowA[i]);
    #pragma unroll
    for (int i = 0; i < 4; ++i)
        afr[1][i] = *reinterpret_cast<const bf16x8*>(wb2_c + rowA[i] + 64);

    __syncthreads();   // Bwin ready; no more barriers

    #pragma unroll
    for (int k = 0; k < 9; ++k) {
        const int dy = k / 3 - 1;              // constant-folded (loop unrolled)
        const int dx = k - (k / 3) * 3 - 1;
        const int rowbase = (ywave + 1 + dy) * 16384;   // Bwin row byte offset

        int baddr[4], c7[4];
        #pragma unroll
        for (int j = 0; j < 4; ++j) {
            int col = j * 16 + lrow + dx;
            col = min(max(col, 0), 63);        // clamp; OOB lanes masked by bits
            baddr[j] = rowbase + col * 256;
            c7[j] = col & 7;
        }
        uint32_t kp[4];
        #pragma unroll
        for (int j = 0; j < 4; ++j)
            kp[j] = 0u - (uint32_t)((bits >> (k * 4 + j)) & 1ull);

        #pragma unroll
        for (int ks = 0; ks < 4; ++ks) {
            const int s = k * 4 + ks;          // flat step 0..35
            bf16x8 bfr[4];
            #pragma unroll
            for (int j = 0; j < 4; ++j) {
                const int slot = ((ks * 4 + quad) ^ c7[j]) * 16;
                bf16x8 v = *reinterpret_cast<const bf16x8*>(Bw + baddr[j] + slot);
                u32x4 t = __builtin_bit_cast(u32x4, v);
                t &= kp[j];
                bfr[j] = __builtin_bit_cast(bf16x8, t);
            }
            #pragma unroll
            for (int i = 0; i < 4; ++i)
                #pragma unroll
                for (int j = 0; j < 4; ++j)
                    acc[i][j] = __builtin_amdgcn_mfma_f32_16x16x32_bf16(
                        afr[s & 1][i], bfr[j], acc[i][j], 0, 0, 0);
            // re-issue this ring slot for step s+2 (stays in flight ~1.5 steps)
            if (s + 2 < 36) {
                const int k2  = (s + 2) >> 2;
                const int ks2 = (s + 2) & 3;
                const char* A2 = wb2_c + k2 * 32768 + ks2 * 64;
                #pragma unroll
                for (int i = 0; i < 4; ++i)
                    afr[s & 1][i] = *reinterpret_cast<const bf16x8*>(A2 + rowA[i]);
            }
        }
    }

    // ---- epilogue: C/D layout col = lane&15 (l), row = quad*4 + r (o)
    #pragma unroll
    for (int i = 0; i < 4; ++i) {
        #pragma unroll
        for (int j = 0; j < 4; ++j) {
            const int l = l0 + wn + j * 16 + lrow;
            #pragma unroll
            for (int r = 0; r < 4; ++r) {
                const int o = wm + i * 16 + quad * 4 + r;
                out[((size_t)b * COUT_ + o) * L_ + l] = acc[i][j][r] + mb[o * L_ + l];
            }
        }
    }
}

// ---------------------------------------------------------------------------
extern "C" void kernel_launch(void* const* d_in, const int* in_sizes, int n_in,
                              void* d_out, int out_size, void* d_ws, size_t ws_size,
                              hipStream_t stream) {
    const float* x      = (const float*)d_in[0];
    const float* mask   = (const float*)d_in[1];
    const float* weight = (const float*)d_in[2];
    const float* mw     = (const float*)d_in[3];
    const float* bias   = (const float*)d_in[4];
    float* out = (float*)d_out;

    char* ws = (char*)d_ws;
    u16*   xTp = (u16*)ws;                                  // 16*4356*128*2 = 17,842,176 B
    u16*   wb2 = (u16*)(ws + 17842176);                     // 294,912 B  [9][128][128] bf16
    float* mb  = (float*)(ws + 17842176 + 294912);          // 2,097,152 B [128][4096] f32

    lmc_pre_kernel<<<dim3(64, 17), 256, 0, stream>>>(x, xTp, mask, mw, bias, weight, mb, wb2);
    lmc_gemm_kernel<<<dim3(32, 16), 256, 0, stream>>>(xTp, wb2, mask, mb, out);
}

// Round 7
// 142.987 us; speedup vs baseline: 1.0854x; 1.0611x over previous
//
#include <hip/hip_runtime.h>
#include <stdint.h>

#define B_    16
#define CIN_  128
#define COUT_ 128
#define H_    64
#define W_    64
#define L_    4096
#define KK_   1152
#define PW_   66                 // padded image dim (halo 1 each side)

typedef unsigned short u16;
typedef __bf16 bf16x8 __attribute__((ext_vector_type(8)));
typedef float  floatx4 __attribute__((ext_vector_type(4)));
typedef uint32_t u32x4 __attribute__((ext_vector_type(4)));

typedef const __attribute__((address_space(1))) uint32_t* gptr_t;
typedef __attribute__((address_space(3))) uint32_t*       lptr_t;

__device__ __forceinline__ void async_copy16(const void* g, void* l) {
    // 64 lanes x 16 B = 1 KB; LDS dest = wave-uniform base + lane*16
    __builtin_amdgcn_global_load_lds((gptr_t)g, (lptr_t)l, 16, 0, 0);
}

__device__ __forceinline__ u16 f2bf(float f) {
    uint32_t u = __builtin_bit_cast(uint32_t, f);
    uint32_t r = u + 0x7FFFu + ((u >> 16) & 1u);   // round-to-nearest-even
    return (u16)(r >> 16);
}

// ---------------------------------------------------------------------------
// P1 fused: blockIdx.y < 16 : x [B][CIN][64][64] f32 -> xTp [B][66][66][CIN] bf16
//           blockIdx.y ==16 : mb[o][l] precompute + weight reorder wb2[k][o][c]
// ---------------------------------------------------------------------------
__global__ void lmc_pre_kernel(const float* __restrict__ x, u16* __restrict__ xTp,
                               const float* __restrict__ mask, const float* __restrict__ mw,
                               const float* __restrict__ bias, const float* __restrict__ w,
                               float* __restrict__ mb, u16* __restrict__ wb2) {
    __shared__ u16 tile[64][CIN_ + 8];
    const int tid = threadIdx.x;

    if (blockIdx.y == 16) {
        const int bid = blockIdx.x;
        const int base = bid * 2304;
        #pragma unroll
        for (int i = 0; i < 9; ++i) {
            const int e = base + i * 256 + tid;
            const int k = e >> 14;
            const int rem = e & 16383;
            const int o = rem >> 7, c = rem & 127;
            wb2[e] = f2bf(w[(size_t)o * KK_ + c * 9 + k]);
        }
        #pragma unroll
        for (int oo = 0; oo < 2; ++oo) {
            const int o = bid * 2 + oo;
            float m[9];
            #pragma unroll
            for (int k = 0; k < 9; ++k) m[k] = mw[o * 9 + k];
            const float bs = bias[o];
            for (int l = tid; l < L_; l += 256) {
                float s = bs;
                #pragma unroll
                for (int k = 0; k < 9; ++k) s += m[k] * mask[k * L_ + l];
                mb[o * L_ + l] = s;
            }
        }
        return;
    }

    const int b = blockIdx.y;
    const int y = blockIdx.x;        // 0..63
    {
        const int c  = tid >> 1;
        const int x0 = (tid & 1) * 32;
        const float* src = x + ((size_t)b * CIN_ + c) * L_ + y * 64 + x0;
        #pragma unroll
        for (int j = 0; j < 32; j += 4) {
            float4 v = *reinterpret_cast<const float4*>(src + j);
            tile[x0 + j + 0][c] = f2bf(v.x);
            tile[x0 + j + 1][c] = f2bf(v.y);
            tile[x0 + j + 2][c] = f2bf(v.z);
            tile[x0 + j + 3][c] = f2bf(v.w);
        }
    }
    __syncthreads();

    u16* dstrow = xTp + ((size_t)(b * PW_ + (y + 1)) * PW_) * CIN_;  // pixel (y+1, 0)
    {
        const int xx   = tid >> 2;
        const int cseg = (tid & 3) * 32;
        u16* dst = dstrow + (size_t)(xx + 1) * CIN_ + cseg;
        #pragma unroll
        for (int i = 0; i < 32; i += 8) {
            *reinterpret_cast<uint4*>(dst + i) =
                *reinterpret_cast<const uint4*>(&tile[xx][cseg + i]);
        }
    }
    const uint4 z = {0u, 0u, 0u, 0u};
    if (tid < 32) {   // x-halo pixels (y+1, 0) and (y+1, 65)
        const int pix = (tid >> 4) ? 65 : 0;
        *reinterpret_cast<uint4*>(dstrow + (size_t)pix * CIN_ + (tid & 15) * 8) = z;
    }
    if (y == 0 || y == 63) {   // y-halo rows 0 / 65
        u16* brow = xTp + ((size_t)(b * PW_ + (y == 0 ? 0 : 65)) * PW_) * CIN_;
        for (int i = tid; i < (PW_ * CIN_) / 8; i += 256)
            reinterpret_cast<uint4*>(brow)[i] = z;
    }
}

// ---------------------------------------------------------------------------
// Main GEMM, c-split K structure:
//   block = 128 thr (2 waves), tile 128o x 64l (1 image row), wave = 64o x 64l.
//   K split into 2 c-halves x 9 taps, K=32 MFMA steps x2 per tap.
//   Bwin: 3 rows x 64 cols x 64ch = 24 KB, staged once per c-phase (L3).
//   A: per-tap 128o x 64c = 16 KB via global_load_lds (L2-hot slab, short drain).
//   40 KB LDS -> 4 blocks/CU, 1024 blocks, 4 independent barrier groups/CU.
//   XOR-8 chunk swizzle on 128 B rows; binary mask + x-halo as AND bits.
// ---------------------------------------------------------------------------
__global__ __launch_bounds__(128, 2)
void lmc_gemm_kernel(const u16* __restrict__ xTp, const u16* __restrict__ wb2,
                     const float* __restrict__ mask, const float* __restrict__ mb,
                     float* __restrict__ out) {
    __shared__ u16 Bwin[3 * 64 * 64];    // 24576 B [row][col][slot*8 halves]
    __shared__ u16 A_lds[128 * 64];      // 16384 B [o][slot*8 halves]

    const int b    = blockIdx.y;
    const int yrow = blockIdx.x;         // image row 0..63
    const int l0   = yrow << 6;
    const int tid  = threadIdx.x;
    const int lane = tid & 63;
    const int wv   = tid >> 6;           // 2 waves
    const int lrow = lane & 15;
    const int quad = lane >> 4;
    const int wm   = wv << 6;            // wave's o-offset (0 or 64)

    const char* xTp_c = (const char*)xTp;
    const char* wb2_c = (const char*)wb2;
    char* Bw = (char*)Bwin;
    char* Al = (char*)A_lds;
    // padded window rows yrow .. yrow+2 (= image rows yrow-1..yrow+1)
    const size_t browbase = ((size_t)(b * PW_) + yrow) * PW_ * 256;

    // ---- stage Bwin for c-half ch: 192 pixels x 128 B, wave wv does 96
    auto stageB = [&](int ch) {
        #pragma unroll
        for (int seg = 0; seg < 12; ++seg) {
            const int p   = wv * 96 + seg * 8 + (lane >> 3);
            const int row = p >> 6, col = p & 63;
            const char* g = xTp_c + browbase + ((size_t)row * PW_ + 1 + col) * 256
                            + ch * 128 + (((lane & 7) ^ (col & 7)) << 4);
            async_copy16(g, Bw + (wv * 96 + seg * 8) * 128);
        }
    };
    // ---- stage A for tap t, c-half ch: 128 o x 128 B, wave wv does 64
    auto stageA = [&](int t, int ch) {
        #pragma unroll
        for (int seg = 0; seg < 8; ++seg) {
            const int o = wv * 64 + seg * 8 + (lane >> 3);
            const char* g = wb2_c + t * 32768 + o * 256 + ch * 128
                            + (((lane & 7) ^ (o & 7)) << 4);
            async_copy16(g, Al + (wv * 64 + seg * 8) * 128);
        }
    };

    // ---- pack 36 bits: bit(k,j) = mask[k][l] != 0 AND x+dx in [0,64)
    uint64_t bits = 0;
    #pragma unroll
    for (int j = 0; j < 4; ++j) {
        const int xl = j * 16 + lrow;            // 0..63
        #pragma unroll
        for (int k = 0; k < 9; ++k) {
            const int dx = k - (k / 3) * 3 - 1;
            const bool xok = (unsigned)(xl + dx) < 64u;
            if (xok && mask[k * L_ + l0 + xl] != 0.0f) bits |= (1ull << (k * 4 + j));
        }
    }

    floatx4 acc[4][4];
    #pragma unroll
    for (int i = 0; i < 4; ++i)
        #pragma unroll
        for (int j = 0; j < 4; ++j)
            acc[i][j] = (floatx4){0.f, 0.f, 0.f, 0.f};

    const int o7 = lrow & 7;   // (o & 7) for all this wave's A-frag rows

    // ---- compute one tap from current A_lds/Bwin (2 ksteps x 16 MFMA)
    auto comp = [&](int k) {
        const int dy = k / 3 - 1;
        const int dx = k - (k / 3) * 3 - 1;
        const int rowbase = (1 + dy) * 8192;
        int baddr[4], c7[4];
        uint32_t kp[4];
        #pragma unroll
        for (int j = 0; j < 4; ++j) {
            int col = j * 16 + lrow + dx;
            col = min(max(col, 0), 63);          // clamp; OOB masked via bits
            baddr[j] = rowbase + col * 128;
            c7[j] = col & 7;
            kp[j] = 0u - (uint32_t)((bits >> (k * 4 + j)) & 1ull);
        }
        #pragma unroll
        for (int ks = 0; ks < 2; ++ks) {
            const int ch = ks * 4 + quad;        // 16B chunk within 128B row
            bf16x8 af[4], bfr[4];
            #pragma unroll
            for (int i = 0; i < 4; ++i)
                af[i] = *reinterpret_cast<const bf16x8*>(
                    Al + (wm + i * 16 + lrow) * 128 + ((ch ^ o7) << 4));
            #pragma unroll
            for (int j = 0; j < 4; ++j) {
                bf16x8 v = *reinterpret_cast<const bf16x8*>(
                    Bw + baddr[j] + ((ch ^ c7[j]) << 4));
                u32x4 t = __builtin_bit_cast(u32x4, v);
                t &= kp[j];
                bfr[j] = __builtin_bit_cast(bf16x8, t);
            }
            #pragma unroll
            for (int i = 0; i < 4; ++i)
                #pragma unroll
                for (int j = 0; j < 4; ++j)
                    acc[i][j] = __builtin_amdgcn_mfma_f32_16x16x32_bf16(
                        af[i], bfr[j], acc[i][j], 0, 0, 0);
        }
    };

    stageB(0);
    stageA(0, 0);
    __syncthreads();

    #pragma unroll
    for (int ch = 0; ch < 2; ++ch) {
        #pragma unroll
        for (int k = 0; k < 9; ++k) {
            comp(k);
            __syncthreads();                       // readers done -> safe to overwrite
            if (k < 8) {
                stageA(k + 1, ch);
                __syncthreads();                   // A[k+1] ready (short L2 drain)
            } else if (ch == 0) {
                stageB(1);
                stageA(0, 1);
                __syncthreads();                   // phase-1 data ready
            }
        }
    }

    // ---- epilogue: C/D layout col = lane&15 (l), row = quad*4 + r (o)
    #pragma unroll
    for (int i = 0; i < 4; ++i) {
        #pragma unroll
        for (int j = 0; j < 4; ++j) {
            const int l = l0 + j * 16 + lrow;
            #pragma unroll
            for (int r = 0; r < 4; ++r) {
                const int o = wm + i * 16 + quad * 4 + r;
                out[((size_t)b * COUT_ + o) * L_ + l] = acc[i][j][r] + mb[o * L_ + l];
            }
        }
    }
}

// ---------------------------------------------------------------------------
extern "C" void kernel_launch(void* const* d_in, const int* in_sizes, int n_in,
                              void* d_out, int out_size, void* d_ws, size_t ws_size,
                              hipStream_t stream) {
    const float* x      = (const float*)d_in[0];
    const float* mask   = (const float*)d_in[1];
    const float* weight = (const float*)d_in[2];
    const float* mw     = (const float*)d_in[3];
    const float* bias   = (const float*)d_in[4];
    float* out = (float*)d_out;

    char* ws = (char*)d_ws;
    u16*   xTp = (u16*)ws;                                  // 16*4356*128*2 = 17,842,176 B
    u16*   wb2 = (u16*)(ws + 17842176);                     // 294,912 B  [9][128][128] bf16
    float* mb  = (float*)(ws + 17842176 + 294912);          // 2,097,152 B [128][4096] f32

    lmc_pre_kernel<<<dim3(64, 17), 256, 0, stream>>>(x, xTp, mask, mw, bias, weight, mb, wb2);
    lmc_gemm_kernel<<<dim3(64, 16), 128, 0, stream>>>(xTp, wb2, mask, mb, out);
}